// Round 5
// baseline (95.885 us; speedup 1.0000x reference)
//
#include <hip/hip_runtime.h>
#include <hip/hip_bf16.h>
#include <math.h>

#define G 4
#define T 2048
#define H 1024
#define E 8
#define LB (G * T / 4)  // 2048 logits blocks (4 tokens each)
#define ZB 2048         // zero-fill blocks in K1

typedef float f4 __attribute__((ext_vector_type(4)));

// ---------------------------------------------------------------------------
// K1 (FUSED): blocks [0,LB) = logits+softmax (fp64, NUMERIC PATH FROZEN —
// absmax=0.0 rounds 2-4); blocks [LB,LB+ZB) = zero-fill of dispatch half
// (store-bound, overlaps the VALU-bound logits); tail blocks = gate/idx pad
// init (gate=0, idx=-1) so K2's rankers only write slots rank<cap.
// ---------------------------------------------------------------------------
__global__ __launch_bounds__(256) void logits_zero_init(
    const float* __restrict__ x, const float* __restrict__ W,
    const float* __restrict__ b, float* __restrict__ probs,
    float* __restrict__ lse2, float* __restrict__ out,
    float* __restrict__ gate, int* __restrict__ idx, unsigned n4d,
    int max_cap) {
  unsigned bid = blockIdx.x;
  unsigned tid = threadIdx.x;

  if (bid < LB) {
    int wave = (int)(bid * 4 + (tid >> 6));
    int lane = tid & 63;
    const float* xr = x + (size_t)wave * H;

    double acc0 = 0, acc1 = 0, acc2 = 0, acc3 = 0;
    double acc4 = 0, acc5 = 0, acc6 = 0, acc7 = 0;
#pragma unroll
    for (int j = 0; j < 4; ++j) {
      int hbase = j * 256 + lane * 4;
      f4 xv = *(const f4*)(xr + hbase);
#pragma unroll
      for (int k = 0; k < 4; ++k) {
        const float* wr = W + (size_t)(hbase + k) * 8;
        f4 w0 = *(const f4*)(wr);
        f4 w1 = *(const f4*)(wr + 4);
        double xd = (double)xv[k];
        acc0 += xd * (double)w0[0];
        acc1 += xd * (double)w0[1];
        acc2 += xd * (double)w0[2];
        acc3 += xd * (double)w0[3];
        acc4 += xd * (double)w1[0];
        acc5 += xd * (double)w1[1];
        acc6 += xd * (double)w1[2];
        acc7 += xd * (double)w1[3];
      }
    }
#pragma unroll
    for (int off = 32; off >= 1; off >>= 1) {
      acc0 += __shfl_xor(acc0, off);
      acc1 += __shfl_xor(acc1, off);
      acc2 += __shfl_xor(acc2, off);
      acc3 += __shfl_xor(acc3, off);
      acc4 += __shfl_xor(acc4, off);
      acc5 += __shfl_xor(acc5, off);
      acc6 += __shfl_xor(acc6, off);
      acc7 += __shfl_xor(acc7, off);
    }
    if (lane == 0) {
      double l0 = acc0 + (double)b[0], l1 = acc1 + (double)b[1];
      double l2 = acc2 + (double)b[2], l3 = acc3 + (double)b[3];
      double l4 = acc4 + (double)b[4], l5 = acc5 + (double)b[5];
      double l6 = acc6 + (double)b[6], l7 = acc7 + (double)b[7];
      double m = fmax(fmax(fmax(l0, l1), fmax(l2, l3)),
                      fmax(fmax(l4, l5), fmax(l6, l7)));
      double p0 = exp(l0 - m), p1 = exp(l1 - m), p2 = exp(l2 - m),
             p3 = exp(l3 - m), p4 = exp(l4 - m), p5 = exp(l5 - m),
             p6 = exp(l6 - m), p7 = exp(l7 - m);
      double s = ((p0 + p1) + (p2 + p3)) + ((p4 + p5) + (p6 + p7));
      double inv = 1.0 / s;
      f4 v0 = {(float)(p0 * inv), (float)(p1 * inv), (float)(p2 * inv),
               (float)(p3 * inv)};
      f4 v1 = {(float)(p4 * inv), (float)(p5 * inv), (float)(p6 * inv),
               (float)(p7 * inv)};
      *(f4*)(probs + (size_t)wave * 8) = v0;
      *(f4*)(probs + (size_t)wave * 8 + 4) = v1;
      double lse = m + log(s);
      lse2[wave] = (float)(lse * lse);
    }
  } else if (bid < LB + ZB) {
    f4* outD = (f4*)out;
    f4 z = {0.0f, 0.0f, 0.0f, 0.0f};
    unsigned stride = ZB * 256u;
    for (unsigned i = (bid - LB) * 256u + tid; i < n4d; i += stride)
      outD[i] = z;
  } else {
    unsigned s = (bid - LB - ZB) * 256u + tid;
    if (s < (unsigned)(G * E * max_cap)) {
      gate[s] = 0.0f;
      idx[s] = -1;
    }
  }
}

// ---------------------------------------------------------------------------
// K2: rank-select, replaces the bitonic sort (R4 post-mortem: 66
// barrier-separated phases ~30us on 32 CUs). Keys unique (prob_bits<<32|~t)
// => token's rank (count of strictly greater keys) == its sorted position ==
// jax.lax.top_k slot. 256 blocks = (expert ge, 256-token chunk); one barrier;
// inner scan is an LDS broadcast read (conflict-free) + u64 cmp.
// ---------------------------------------------------------------------------
__global__ __launch_bounds__(256) void rank_select(
    const float* __restrict__ probs, float* __restrict__ gate,
    int* __restrict__ idx, int max_cap, int ec) {
  __shared__ unsigned long long keys[T];
  unsigned bid = blockIdx.x;  // 0..255
  int ge = (int)(bid >> 3);
  int chunk = (int)(bid & 7);
  int g = ge >> 3, e = ge & 7;
  int tid = threadIdx.x;

  for (int t = tid; t < T; t += 256) {
    float p = probs[((size_t)g * T + t) * 8 + e];
    keys[t] =
        ((unsigned long long)__float_as_uint(p) << 32) | (unsigned)(~t);
  }
  __syncthreads();

  int myt = chunk * 256 + tid;
  unsigned long long k0 = keys[myt];
  int rank = 0;
#pragma unroll 8
  for (int j = 0; j < T; ++j) rank += (keys[j] > k0) ? 1 : 0;

  const double factors[8] = {0.5, 0.75, 1.0, 1.0, 1.25, 1.25, 1.5, 1.5};
  int cap = (int)((double)ec * factors[e]);
  if (rank < cap) {
    gate[(size_t)ge * max_cap + rank] = __uint_as_float((unsigned)(k0 >> 32));
    idx[(size_t)ge * max_cap + rank] = myt;
  }
}

// ---------------------------------------------------------------------------
// K3 (FUSED): block 0 = z-loss reduce + trailing scalars; blocks [1,1+scb] =
// scatter ones into pre-zeroed dispatch half; rest = combine broadcast-fill
// (gate reads 48 KB L2-resident; pure f4 store stream).
// ---------------------------------------------------------------------------
template <int MC4S>
__global__ __launch_bounds__(256) void scatter_and_combine(
    const float* __restrict__ gate, const int* __restrict__ idx,
    const float* __restrict__ lse2, float* __restrict__ out, unsigned n4d,
    unsigned mc4_rt, int max_cap, unsigned scb) {
  const unsigned mc4 = MC4S ? (unsigned)MC4S : mc4_rt;
  unsigned tid = threadIdx.x;
  unsigned bid = blockIdx.x;

  if (bid == 0) {
    __shared__ double red[256];
    double s = 0.0;
    for (int i = tid; i < G * T; i += 256) s += (double)lse2[i];
    red[tid] = s;
    __syncthreads();
    for (int off = 128; off > 0; off >>= 1) {
      if ((int)tid < off) red[tid] += red[tid + off];
      __syncthreads();
    }
    if (tid == 0) {
      size_t ne = (size_t)n4d * 4;
      out[2 * ne] = 0.0f;                                   // auxiliary_loss
      out[2 * ne + 1] = (float)(red[0] / (double)(G * T));  // z_loss
    }
    return;
  }
  if (bid <= scb) {
    unsigned s = (bid - 1) * 256u + tid;
    if (s < (unsigned)(G * E) * (unsigned)max_cap) {
      unsigned ge = s / (unsigned)max_cap;
      unsigned c = s - ge * (unsigned)max_cap;
      int t = idx[s];
      if (t >= 0) out[((size_t)ge * T + t) * (unsigned)max_cap + c] = 1.0f;
    }
    return;
  }

  f4* outC = (f4*)out + n4d;
  const f4* gate4 = (const f4*)gate;
  unsigned fb = bid - 1 - scb;
  unsigned nfb = gridDim.x - 1 - scb;
  unsigned stride = nfb * 256u;
  for (unsigned i = fb * 256u + tid; i < n4d; i += stride) {
    unsigned c4 = i % mc4;
    unsigned rem = i / mc4;
    unsigned ge = rem >> 11;
    outC[i] = gate4[ge * mc4 + c4];
  }
}

extern "C" void kernel_launch(void* const* d_in, const int* in_sizes, int n_in,
                              void* d_out, int out_size, void* d_ws,
                              size_t ws_size, hipStream_t stream) {
  const float* x = (const float*)d_in[0];
  const float* W = (const float*)d_in[1];
  const float* b = (const float*)d_in[2];

  // Derive max_cap from out_size: out = 2*G*E*T*max_cap + 2 scalars.
  long long body = (long long)out_size - 2;
  int max_cap = (int)(body / (2LL * G * E * T));  // 384 for ec=256
  if (max_cap <= 0) return;
  int ec = (2 * max_cap) / 3;  // max factor is 1.5

  float* ws = (float*)d_ws;
  float* probs = ws;                     // G*T*E = 65536 floats
  float* lse2 = ws + (size_t)G * T * E;  // 8192 floats
  float* gate = lse2 + (size_t)G * T;    // G*E*max_cap floats
  int* idx = (int*)(gate + (size_t)G * E * max_cap);

  unsigned n4d = (unsigned)((long long)G * E * T * max_cap / 4);  // per array
  unsigned scb = (unsigned)((G * E * max_cap + 255) / 256);
  unsigned initb = scb;  // same count for pad-init

  logits_zero_init<<<LB + ZB + initb, 256, 0, stream>>>(
      x, W, b, probs, lse2, (float*)d_out, gate, idx, n4d, max_cap);
  rank_select<<<256, 256, 0, stream>>>(probs, gate, idx, max_cap, ec);

  int blocks = 6144;
  if (max_cap == 384) {
    scatter_and_combine<96><<<blocks, 256, 0, stream>>>(
        gate, idx, lse2, (float*)d_out, n4d, 96u, max_cap, scb);
  } else {
    scatter_and_combine<0><<<blocks, 256, 0, stream>>>(
        gate, idx, lse2, (float*)d_out, n4d, (unsigned)(max_cap / 4), max_cap,
        scb);
  }
}

// Round 6
// 83.662 us; speedup vs baseline: 1.1461x; 1.1461x over previous
//
#include <hip/hip_runtime.h>
#include <hip/hip_bf16.h>
#include <math.h>

#define G 4
#define T 2048
#define H 1024
#define E 8
#define LB 2048  // logits blocks (4 tokens each)
#define ZB1 1024 // zero-fill blocks in K1 (lower half of dispatch)
#define RB 256   // rank blocks in K2
#define ZB2 1024 // zero-fill blocks in K2 (upper half of dispatch)

typedef float f4 __attribute__((ext_vector_type(4)));
typedef unsigned long long u64;
typedef unsigned long long u64v2 __attribute__((ext_vector_type(2)));

// ---------------------------------------------------------------------------
// K1 (FUSED): [0,LB) logits+softmax -> packed u64 keys (fp64 path FROZEN,
// absmax=0.0 R2-R5). key = prob_bits<<32 | ~t  (unique; desc order == value
// desc, index asc == jax.lax.top_k). [LB,LB+ZB1) zero lower half of dispatch.
// Tail: gate=0 / idx=-1 pad init.
// ---------------------------------------------------------------------------
__global__ __launch_bounds__(256) void k1_logits_zero_init(
    const float* __restrict__ x, const float* __restrict__ W,
    const float* __restrict__ b, u64* __restrict__ keys,
    float* __restrict__ lse2, float* __restrict__ out,
    float* __restrict__ gate, int* __restrict__ idx, unsigned n4d,
    int max_cap) {
  unsigned bid = blockIdx.x;
  unsigned tid = threadIdx.x;

  if (bid < LB) {
    int wave = (int)(bid * 4 + (tid >> 6));
    int lane = tid & 63;
    const float* xr = x + (size_t)wave * H;

    double acc0 = 0, acc1 = 0, acc2 = 0, acc3 = 0;
    double acc4 = 0, acc5 = 0, acc6 = 0, acc7 = 0;
#pragma unroll
    for (int j = 0; j < 4; ++j) {
      int hbase = j * 256 + lane * 4;
      f4 xv = *(const f4*)(xr + hbase);
#pragma unroll
      for (int k = 0; k < 4; ++k) {
        const float* wr = W + (size_t)(hbase + k) * 8;
        f4 w0 = *(const f4*)(wr);
        f4 w1 = *(const f4*)(wr + 4);
        double xd = (double)xv[k];
        acc0 += xd * (double)w0[0];
        acc1 += xd * (double)w0[1];
        acc2 += xd * (double)w0[2];
        acc3 += xd * (double)w0[3];
        acc4 += xd * (double)w1[0];
        acc5 += xd * (double)w1[1];
        acc6 += xd * (double)w1[2];
        acc7 += xd * (double)w1[3];
      }
    }
#pragma unroll
    for (int off = 32; off >= 1; off >>= 1) {
      acc0 += __shfl_xor(acc0, off);
      acc1 += __shfl_xor(acc1, off);
      acc2 += __shfl_xor(acc2, off);
      acc3 += __shfl_xor(acc3, off);
      acc4 += __shfl_xor(acc4, off);
      acc5 += __shfl_xor(acc5, off);
      acc6 += __shfl_xor(acc6, off);
      acc7 += __shfl_xor(acc7, off);
    }
    if (lane == 0) {
      double l0 = acc0 + (double)b[0], l1 = acc1 + (double)b[1];
      double l2 = acc2 + (double)b[2], l3 = acc3 + (double)b[3];
      double l4 = acc4 + (double)b[4], l5 = acc5 + (double)b[5];
      double l6 = acc6 + (double)b[6], l7 = acc7 + (double)b[7];
      double m = fmax(fmax(fmax(l0, l1), fmax(l2, l3)),
                      fmax(fmax(l4, l5), fmax(l6, l7)));
      double pr[8];
      pr[0] = exp(l0 - m);
      pr[1] = exp(l1 - m);
      pr[2] = exp(l2 - m);
      pr[3] = exp(l3 - m);
      pr[4] = exp(l4 - m);
      pr[5] = exp(l5 - m);
      pr[6] = exp(l6 - m);
      pr[7] = exp(l7 - m);
      double s = ((pr[0] + pr[1]) + (pr[2] + pr[3])) +
                 ((pr[4] + pr[5]) + (pr[6] + pr[7]));
      double inv = 1.0 / s;
      int g = wave >> 11;
      int t = wave & (T - 1);
      u64* kb = keys + (size_t)g * 8 * T + t;
#pragma unroll
      for (int e = 0; e < 8; ++e) {
        float pf = (float)(pr[e] * inv);
        kb[(size_t)e * T] =
            ((u64)__float_as_uint(pf) << 32) | (unsigned)(~t);
      }
      double lse = m + log(s);
      lse2[wave] = (float)(lse * lse);
    }
  } else if (bid < LB + ZB1) {
    f4* outD = (f4*)out;
    f4 z = {0.0f, 0.0f, 0.0f, 0.0f};
    unsigned half = n4d >> 1;
    unsigned stride = ZB1 * 256u;
    for (unsigned i = (bid - LB) * 256u + tid; i < half; i += stride)
      outD[i] = z;
  } else {
    unsigned s = (bid - LB - ZB1) * 256u + tid;
    if (s < (unsigned)(G * E * max_cap)) {
      gate[s] = 0.0f;
      idx[s] = -1;
    }
  }
}

// ---------------------------------------------------------------------------
// K2 (FUSED): [0,RB) rank-select via LDS broadcast scan; [RB,..) zero upper
// half of dispatch (overlaps the scan). Rank block: stage 2048 keys in LDS,
// each thread counts strictly-greater keys over all 2048 via ds_read_b128
// broadcast (2 keys/instr, conflict-free), 4-deep register prefetch + 4
// accumulators (R5 lesson: 1 wave/SIMD + per-key ds_read_b64 = latency-bound).
// Unique keys => rank == top_k slot; rank<cap writes gate/idx.
// ---------------------------------------------------------------------------
__global__ __launch_bounds__(256) void k2_rank_zero(
    const u64* __restrict__ keys, float* __restrict__ gate,
    int* __restrict__ idx, float* __restrict__ out, unsigned n4d, int max_cap,
    int ec) {
  __shared__ u64 lk[T];
  unsigned bid = blockIdx.x;
  unsigned tid = threadIdx.x;

  if (bid < RB) {
    int ge = (int)(bid >> 3);
    int chunk = (int)(bid & 7);
    const u64* kcol = keys + (size_t)ge * T;
    for (int t = tid; t < T; t += 256) lk[t] = kcol[t];
    __syncthreads();

    int myt = chunk * 256 + (int)tid;
    u64 mine = lk[myt];

    const u64v2* k2p = (const u64v2*)lk;
    int r0 = 0, r1 = 0, r2 = 0, r3 = 0;
    u64v2 p0 = k2p[0], p1 = k2p[1], p2 = k2p[2], p3 = k2p[3];
    for (int j = 4; j < T / 2; j += 4) {
      u64v2 q0 = k2p[j], q1 = k2p[j + 1], q2 = k2p[j + 2], q3 = k2p[j + 3];
      r0 += (int)(p0.x > mine) + (int)(p0.y > mine);
      r1 += (int)(p1.x > mine) + (int)(p1.y > mine);
      r2 += (int)(p2.x > mine) + (int)(p2.y > mine);
      r3 += (int)(p3.x > mine) + (int)(p3.y > mine);
      p0 = q0;
      p1 = q1;
      p2 = q2;
      p3 = q3;
    }
    r0 += (int)(p0.x > mine) + (int)(p0.y > mine);
    r1 += (int)(p1.x > mine) + (int)(p1.y > mine);
    r2 += (int)(p2.x > mine) + (int)(p2.y > mine);
    r3 += (int)(p3.x > mine) + (int)(p3.y > mine);
    int rank = (r0 + r1) + (r2 + r3);

    const double factors[8] = {0.5, 0.75, 1.0, 1.0, 1.25, 1.25, 1.5, 1.5};
    int cap = (int)((double)ec * factors[ge & 7]);
    if (rank < cap) {
      gate[(size_t)ge * max_cap + rank] =
          __uint_as_float((unsigned)(mine >> 32));
      idx[(size_t)ge * max_cap + rank] = myt;
    }
  } else {
    f4* outD = (f4*)out;
    f4 z = {0.0f, 0.0f, 0.0f, 0.0f};
    unsigned half = n4d >> 1;
    unsigned stride = ZB2 * 256u;
    for (unsigned i = half + (bid - RB) * 256u + tid; i < n4d; i += stride)
      outD[i] = z;
  }
}

// ---------------------------------------------------------------------------
// K3 (FUSED): block 0 = z-loss reduce + trailing scalars; blocks [1,1+scb] =
// scatter ones into pre-zeroed dispatch half; rest = combine broadcast-fill
// (gate reads 48 KB L1/L2-resident; pure f4 store stream).
// ---------------------------------------------------------------------------
template <int MC4S>
__global__ __launch_bounds__(256) void scatter_and_combine(
    const float* __restrict__ gate, const int* __restrict__ idx,
    const float* __restrict__ lse2, float* __restrict__ out, unsigned n4d,
    unsigned mc4_rt, int max_cap, unsigned scb) {
  const unsigned mc4 = MC4S ? (unsigned)MC4S : mc4_rt;
  unsigned tid = threadIdx.x;
  unsigned bid = blockIdx.x;

  if (bid == 0) {
    __shared__ double red[256];
    double s = 0.0;
    for (int i = tid; i < G * T; i += 256) s += (double)lse2[i];
    red[tid] = s;
    __syncthreads();
    for (int off = 128; off > 0; off >>= 1) {
      if ((int)tid < off) red[tid] += red[tid + off];
      __syncthreads();
    }
    if (tid == 0) {
      size_t ne = (size_t)n4d * 4;
      out[2 * ne] = 0.0f;                                   // auxiliary_loss
      out[2 * ne + 1] = (float)(red[0] / (double)(G * T));  // z_loss
    }
    return;
  }
  if (bid <= scb) {
    unsigned s = (bid - 1) * 256u + tid;
    if (s < (unsigned)(G * E) * (unsigned)max_cap) {
      unsigned ge = s / (unsigned)max_cap;
      unsigned c = s - ge * (unsigned)max_cap;
      int t = idx[s];
      if (t >= 0) out[((size_t)ge * T + t) * (unsigned)max_cap + c] = 1.0f;
    }
    return;
  }

  f4* outC = (f4*)out + n4d;
  const f4* gate4 = (const f4*)gate;
  unsigned fb = bid - 1 - scb;
  unsigned nfb = gridDim.x - 1 - scb;
  unsigned stride = nfb * 256u;
  for (unsigned i = fb * 256u + tid; i < n4d; i += stride) {
    unsigned c4 = i % mc4;
    unsigned rem = i / mc4;
    unsigned ge = rem >> 11;
    outC[i] = gate4[ge * mc4 + c4];
  }
}

extern "C" void kernel_launch(void* const* d_in, const int* in_sizes, int n_in,
                              void* d_out, int out_size, void* d_ws,
                              size_t ws_size, hipStream_t stream) {
  const float* x = (const float*)d_in[0];
  const float* W = (const float*)d_in[1];
  const float* b = (const float*)d_in[2];

  // Derive max_cap from out_size: out = 2*G*E*T*max_cap + 2 scalars.
  long long body = (long long)out_size - 2;
  int max_cap = (int)(body / (2LL * G * E * T));  // 384 for ec=256
  if (max_cap <= 0) return;
  int ec = (2 * max_cap) / 3;  // max factor is 1.5

  u64* keys = (u64*)d_ws;                           // 32*2048 u64 = 512 KB
  float* lse2 = (float*)(keys + (size_t)G * E * T); // 8192 floats
  float* gate = lse2 + (size_t)G * T;               // G*E*max_cap floats
  int* idx = (int*)(gate + (size_t)G * E * max_cap);

  unsigned n4d = (unsigned)((long long)G * E * T * max_cap / 4);  // per array
  unsigned scb = (unsigned)((G * E * max_cap + 255) / 256);       // 48

  k1_logits_zero_init<<<LB + ZB1 + scb, 256, 0, stream>>>(
      x, W, b, keys, lse2, (float*)d_out, gate, idx, n4d, max_cap);
  k2_rank_zero<<<RB + ZB2, 256, 0, stream>>>(keys, gate, idx, (float*)d_out,
                                             n4d, max_cap, ec);

  int blocks = 6144;
  if (max_cap == 384) {
    scatter_and_combine<96><<<blocks, 256, 0, stream>>>(
        gate, idx, lse2, (float*)d_out, n4d, 96u, max_cap, scb);
  } else {
    scatter_and_combine<0><<<blocks, 256, 0, stream>>>(
        gate, idx, lse2, (float*)d_out, n4d, (unsigned)(max_cap / 4), max_cap,
        scb);
  }
}